// Round 1
// baseline (4770.435 us; speedup 1.0000x reference)
//
#include <hip/hip_runtime.h>
#include <cstdint>
#include <cstddef>

#define B_  2
#define H_  8
#define C_  2048
#define HW_ 64
#define HD_ 512   // H_*HW_

// ---------------- Projection + rotary phase ----------------
// grid: (C_/32, B_*H_), block 256
// Writes Qr,Qi,Kr,Ki,V as [b,h,c,j] planes (bh-major).
__global__ __launch_bounds__(256) void proj_kernel(
    const float* __restrict__ x, const float* __restrict__ WQ,
    const float* __restrict__ WK, const float* __restrict__ WV,
    const float* __restrict__ theta,
    float* __restrict__ Qr, float* __restrict__ Qi,
    float* __restrict__ Kr, float* __restrict__ Ki,
    float* __restrict__ V)
{
    __shared__ float sW[3][64][65];
    __shared__ float sx[32][65];
    int tid = threadIdx.x;
    int bh = blockIdx.y; int h = bh & 7; int b = bh >> 3;
    int c0 = blockIdx.x * 32;
    for (int t = tid; t < 64 * 64; t += 256) {
        int j = t & 63, i = t >> 6;
        int g = (h * 64 + i) * 64 + j;
        sW[0][i][j] = WQ[g];
        sW[1][i][j] = WK[g];
        sW[2][i][j] = WV[g];
    }
    for (int t = tid; t < 32 * 64; t += 256) {
        int i = t & 63, c = t >> 6;
        sx[c][i] = x[((size_t)(b * C_ + c0 + c)) * HD_ + h * 64 + i];
    }
    __syncthreads();
    int j = tid & 63, cg = tid >> 6;   // cg 0..3, 8 c's each
    float aq[8] = {}, ak[8] = {}, av[8] = {};
    for (int i = 0; i < 64; ++i) {
        float w0 = sW[0][i][j], w1 = sW[1][i][j], w2 = sW[2][i][j];
        #pragma unroll
        for (int cc = 0; cc < 8; ++cc) {
            float xv = sx[cg * 8 + cc][i];
            aq[cc] += xv * w0;
            ak[cc] += xv * w1;
            av[cc] += xv * w2;
        }
    }
    float th = theta[h * 64 + j];
    #pragma unroll
    for (int cc = 0; cc < 8; ++cc) {
        int c = c0 + cg * 8 + cc;
        float sn, cs;
        sincosf((float)c * th, &sn, &cs);
        size_t o = ((size_t)bh * C_ + c) * HW_ + j;
        Qr[o] = aq[cc] * cs; Qi[o] = aq[cc] * sn;
        Kr[o] = ak[cc] * cs; Ki[o] = -ak[cc] * sn;
        V[o]  = av[cc];
    }
}

// ---------------- Retention core + per-row L2 normalize ----------------
// grid: (C_/32 query tiles, B_*H_), block 256.
// Out: OHr/OHi as [b, c, h, i]  (rows of 512 = h*64+i for the GEMMs)
__global__ __launch_bounds__(256) void retention_kernel(
    const float* __restrict__ Qr, const float* __restrict__ Qi,
    const float* __restrict__ Kr, const float* __restrict__ Ki,
    const float* __restrict__ V,
    float* __restrict__ OHr, float* __restrict__ OHi,
    const float* __restrict__ gamma, const float* __restrict__ qk_scale)
{
    __shared__ float sQr[64][34], sQi[64][34];   // [i][c], pad->bank-safe col reads
    __shared__ float sKr[64][34], sKi[64][34];   // [i][d]
    __shared__ float sSr[32][32], sSi[32][32];   // [d][c]
    int tid = threadIdx.x;
    int qt = blockIdx.x, bh = blockIdx.y;
    int h = bh & 7, b = bh >> 3;
    int qc0 = qt * 32;
    size_t base = (size_t)bh * (C_ * HW_);
    for (int t = tid; t < 32 * 64; t += 256) {
        int i = t & 63, c = t >> 6;
        size_t g = base + (size_t)(qc0 + c) * HW_ + i;
        sQr[i][c] = Qr[g];
        sQi[i][c] = Qi[g];
    }
    float lg = log2f(gamma[h]);
    float inv_scale = 1.0f / qk_scale[0];
    float o_r[8] = {}, o_i[8] = {};
    int cq = tid & 31, ig = tid >> 5;       // phase-B map: (c in tile, i-block of 8)
    int cgrp = tid & 15, dgrp = tid >> 4;   // phase-A map: 2c x 2d per thread
    int c0 = cgrp * 2, d0 = dgrp * 2;
    __syncthreads();
    for (int kc0 = 0; kc0 < qc0 + 32; kc0 += 32) {
        for (int t = tid; t < 32 * 64; t += 256) {
            int i = t & 63, d = t >> 6;
            size_t g = base + (size_t)(kc0 + d) * HW_ + i;
            sKr[i][d] = Kr[g];
            sKi[i][d] = Ki[g];
        }
        __syncthreads();
        // phase A: 2x2 complex scores per thread, K-dim = 64
        float rr00 = 0, rr01 = 0, rr10 = 0, rr11 = 0;
        float im00 = 0, im01 = 0, im10 = 0, im11 = 0;
        #pragma unroll 4
        for (int i = 0; i < 64; ++i) {
            float qr0 = sQr[i][c0], qr1 = sQr[i][c0 + 1];
            float qi0 = sQi[i][c0], qi1 = sQi[i][c0 + 1];
            float kr0 = sKr[i][d0], kr1 = sKr[i][d0 + 1];
            float ki0 = sKi[i][d0], ki1 = sKi[i][d0 + 1];
            rr00 += qr0 * kr0 - qi0 * ki0;  im00 += qr0 * ki0 + qi0 * kr0;
            rr01 += qr0 * kr1 - qi0 * ki1;  im01 += qr0 * ki1 + qi0 * kr1;
            rr10 += qr1 * kr0 - qi1 * ki0;  im10 += qr1 * ki0 + qi1 * kr0;
            rr11 += qr1 * kr1 - qi1 * ki1;  im11 += qr1 * ki1 + qi1 * kr1;
        }
        {
            int qcA = qc0 + c0, qcB = qcA + 1;
            int kdA = kc0 + d0, kdB = kdA + 1;
            auto wf = [&](int delta) {
                return delta >= 0 ? exp2f(lg * (float)delta) * inv_scale : 0.0f;
            };
            float w00 = wf(qcA - kdA), w01 = wf(qcA - kdB);
            float w10 = wf(qcB - kdA), w11 = wf(qcB - kdB);
            sSr[d0][c0]         = w00 * rr00;  sSi[d0][c0]         = w00 * im00;
            sSr[d0 + 1][c0]     = w01 * rr01;  sSi[d0 + 1][c0]     = w01 * im01;
            sSr[d0][c0 + 1]     = w10 * rr10;  sSi[d0][c0 + 1]     = w10 * im10;
            sSr[d0 + 1][c0 + 1] = w11 * rr11;  sSi[d0 + 1][c0 + 1] = w11 * im11;
        }
        __syncthreads();
        // phase B: O[c, i] += S[c,d] * V[d,i]; V from global (broadcast, L1-hot)
        const float* Vg = V + base + (size_t)kc0 * HW_ + ig * 8;
        #pragma unroll 8
        for (int d = 0; d < 32; ++d) {
            float sr = sSr[d][cq], si = sSi[d][cq];
            const float4 v0 = *(const float4*)(Vg + (size_t)d * HW_);
            const float4 v1 = *(const float4*)(Vg + (size_t)d * HW_ + 4);
            o_r[0] += sr * v0.x; o_i[0] += si * v0.x;
            o_r[1] += sr * v0.y; o_i[1] += si * v0.y;
            o_r[2] += sr * v0.z; o_i[2] += si * v0.z;
            o_r[3] += sr * v0.w; o_i[3] += si * v0.w;
            o_r[4] += sr * v1.x; o_i[4] += si * v1.x;
            o_r[5] += sr * v1.y; o_i[5] += si * v1.y;
            o_r[6] += sr * v1.z; o_i[6] += si * v1.z;
            o_r[7] += sr * v1.w; o_i[7] += si * v1.w;
        }
        __syncthreads();
    }
    // per-(b,c,h) L2 norm over all 64 i (8 ig-groups x 8)
    float ss = 0;
    #pragma unroll
    for (int k = 0; k < 8; ++k) ss += o_r[k] * o_r[k] + o_i[k] * o_i[k];
    sSr[ig][cq] = ss;
    __syncthreads();
    float tot = 0;
    #pragma unroll
    for (int g2 = 0; g2 < 8; ++g2) tot += sSr[g2][cq];
    float rn = 1.0f / sqrtf(tot);
    size_t o = ((size_t)(b * C_ + qc0 + cq) * H_ + h) * HW_ + ig * 8;
    #pragma unroll
    for (int k = 0; k < 8; ++k) {
        OHr[o + k] = o_r[k] * rn;
        OHi[o + k] = o_i[k] * rn;
    }
}

// ---------------- fp32 GEMM: C[M,N] = A[M,K]*B[K,N] ----------------
// BM=BN=128, BK=8, 256 threads, 8x8 micro-tile.
// mode 0: plain store; mode 1: complex interleave (rows [0,M/2) = re, rest = im);
// mode 2: store real plane only.
__global__ __launch_bounds__(256) void gemm_kernel(
    const float* __restrict__ A, const float* __restrict__ Bm,
    float* __restrict__ Cout, int M, int N, int K, int mode)
{
    __shared__ float sA[8][132];   // 132 floats = 528B rows, 16B-aligned
    __shared__ float sB[8][132];
    int tid = threadIdx.x;
    int bm = blockIdx.x * 128, bn = blockIdx.y * 128;
    int tx = tid & 15, ty = tid >> 4;
    int m0 = ty * 8, n0 = tx * 8;
    float acc[8][8] = {};
    for (int k0 = 0; k0 < K; k0 += 8) {
        for (int t = tid; t < 1024; t += 256) {
            int kk = t & 7, m = t >> 3;
            sA[kk][m] = A[(size_t)(bm + m) * K + k0 + kk];
        }
        for (int t = tid; t < 1024; t += 256) {
            int n = t & 127, kk = t >> 7;
            sB[kk][n] = Bm[(size_t)(k0 + kk) * N + bn + n];
        }
        __syncthreads();
        #pragma unroll
        for (int kk = 0; kk < 8; ++kk) {
            float a_[8], b_[8];
            *(float4*)&a_[0] = *(const float4*)&sA[kk][m0];
            *(float4*)&a_[4] = *(const float4*)&sA[kk][m0 + 4];
            *(float4*)&b_[0] = *(const float4*)&sB[kk][n0];
            *(float4*)&b_[4] = *(const float4*)&sB[kk][n0 + 4];
            #pragma unroll
            for (int im = 0; im < 8; ++im)
                #pragma unroll
                for (int in = 0; in < 8; ++in)
                    acc[im][in] += a_[im] * b_[in];
        }
        __syncthreads();
    }
    int half = M >> 1;
    for (int im = 0; im < 8; ++im) {
        int m = bm + m0 + im;
        for (int in = 0; in < 8; ++in) {
            int n = bn + n0 + in;
            float vv = acc[im][in];
            if (mode == 0) {
                Cout[(size_t)m * N + n] = vv;
            } else if (mode == 1) {
                if (m < half) Cout[2 * ((size_t)m * N + n)] = vv;
                else          Cout[2 * ((size_t)(m - half) * N + n) + 1] = vv;
            } else {
                if (m < half) Cout[(size_t)m * N + n] = vv;
            }
        }
    }
}

// ---------------- complex gate: oh' = oh*g / (1 + exp(-2g)), g complex ----------------
__global__ __launch_bounds__(256) void gate_kernel(
    const float* __restrict__ OHr, const float* __restrict__ OHi,
    const float* __restrict__ G,
    float* __restrict__ O2r, float* __restrict__ O2i, int n)
{
    int idx = blockIdx.x * 256 + threadIdx.x;
    if (idx >= n) return;
    float gr = G[idx], gi = G[idx + n];
    float hr = OHr[idx], hi = OHi[idx];
    float e = expf(-2.0f * gr);
    float sn, cs;
    sincosf(2.0f * gi, &sn, &cs);
    float dr = 1.0f + e * cs;     // 1 + exp(-2g) = (1 + e*cos(2gi)) - i*e*sin(2gi)
    float di = -e * sn;
    float nr = hr * gr - hi * gi; // oh * g
    float ni = hr * gi + hi * gr;
    float inv = 1.0f / (dr * dr + di * di);
    O2r[idx] = (nr * dr + ni * di) * inv;
    O2i[idx] = (ni * dr - nr * di) * inv;
}

extern "C" void kernel_launch(void* const* d_in, const int* in_sizes, int n_in,
                              void* d_out, int out_size, void* d_ws, size_t ws_size,
                              hipStream_t stream)
{
    const float* x     = (const float*)d_in[0];
    const float* WQ    = (const float*)d_in[1];
    const float* WK    = (const float*)d_in[2];
    const float* WV    = (const float*)d_in[3];
    const float* theta = (const float*)d_in[4];
    const float* gamma = (const float*)d_in[5];
    // d_in[6] target_norm: dead in reference
    const float* qk    = (const float*)d_in[7];
    const float* WO    = (const float*)d_in[8];
    const float* WG    = (const float*)d_in[9];
    float* out = (float*)d_out;
    float* w = (float*)d_ws;

    const size_t N1 = (size_t)B_ * H_ * C_ * HW_;  // 2,097,152 (also = B*C*512)
    float *Qr = w,            *Qi = w + N1,      *Kr = w + 2 * N1,
          *Ki = w + 3 * N1,   *V  = w + 4 * N1;
    float *OHr = w + 5 * N1,  *OHi = w + 6 * N1;  // contiguous -> stacked GEMM A
    float *G   = w + 7 * N1;                      // 2*N1 (re plane, im plane)
    float *O2r = w + 9 * N1,  *O2i = w + 10 * N1; // contiguous pair

    proj_kernel<<<dim3(C_ / 32, B_ * H_), 256, 0, stream>>>(
        x, WQ, WK, WV, theta, Qr, Qi, Kr, Ki, V);
    retention_kernel<<<dim3(C_ / 32, B_ * H_), 256, 0, stream>>>(
        Qr, Qi, Kr, Ki, V, OHr, OHi, gamma, qk);

    const int M = 2 * B_ * C_;  // 8192 rows: [re; im] planes
    gemm_kernel<<<dim3(M / 128, HD_ / 128), 256, 0, stream>>>(
        OHr, WG, G, M, HD_, HD_, 0);

    int n1i = (int)N1;
    gate_kernel<<<dim3((n1i + 255) / 256), 256, 0, stream>>>(
        OHr, OHi, G, O2r, O2i, n1i);

    int outmode = (out_size >= (int)(2 * N1)) ? 1 : 2;  // complex interleave vs real-only
    gemm_kernel<<<dim3(M / 128, HD_ / 128), 256, 0, stream>>>(
        O2r, WO, out, M, HD_, HD_, outmode);
}

// Round 2
// 1209.855 us; speedup vs baseline: 3.9430x; 3.9430x over previous
//
#include <hip/hip_runtime.h>
#include <cstdint>
#include <cstddef>

#define B_  2
#define H_  8
#define C_  2048
#define HW_ 64
#define HD_ 512   // H_*HW_

// ---------------- Projection + rotary phase ----------------
// grid: (C_/32, B_*H_), block 256
// Writes Qr,Qi,Kr,Ki,V as [b,h,c,j] planes (bh-major).
__global__ __launch_bounds__(256) void proj_kernel(
    const float* __restrict__ x, const float* __restrict__ WQ,
    const float* __restrict__ WK, const float* __restrict__ WV,
    const float* __restrict__ theta,
    float* __restrict__ Qr, float* __restrict__ Qi,
    float* __restrict__ Kr, float* __restrict__ Ki,
    float* __restrict__ V)
{
    __shared__ float sW[3][64][65];
    __shared__ float sx[32][65];
    int tid = threadIdx.x;
    int bh = blockIdx.y; int h = bh & 7; int b = bh >> 3;
    int c0 = blockIdx.x * 32;
    for (int t = tid; t < 64 * 64; t += 256) {
        int j = t & 63, i = t >> 6;
        int g = (h * 64 + i) * 64 + j;
        sW[0][i][j] = WQ[g];
        sW[1][i][j] = WK[g];
        sW[2][i][j] = WV[g];
    }
    for (int t = tid; t < 32 * 64; t += 256) {
        int i = t & 63, c = t >> 6;
        sx[c][i] = x[((size_t)(b * C_ + c0 + c)) * HD_ + h * 64 + i];
    }
    __syncthreads();
    int j = tid & 63, cg = tid >> 6;   // cg 0..3, 8 c's each
    float aq[8] = {}, ak[8] = {}, av[8] = {};
    for (int i = 0; i < 64; ++i) {
        float w0 = sW[0][i][j], w1 = sW[1][i][j], w2 = sW[2][i][j];
        #pragma unroll
        for (int cc = 0; cc < 8; ++cc) {
            float xv = sx[cg * 8 + cc][i];
            aq[cc] += xv * w0;
            ak[cc] += xv * w1;
            av[cc] += xv * w2;
        }
    }
    float th = theta[h * 64 + j];
    #pragma unroll
    for (int cc = 0; cc < 8; ++cc) {
        int c = c0 + cg * 8 + cc;
        float sn, cs;
        sincosf((float)c * th, &sn, &cs);
        size_t o = ((size_t)bh * C_ + c) * HW_ + j;
        Qr[o] = aq[cc] * cs; Qi[o] = aq[cc] * sn;
        Kr[o] = ak[cc] * cs; Ki[o] = -ak[cc] * sn;
        V[o]  = av[cc];
    }
}

// ---------------- Retention core + per-row L2 normalize ----------------
// grid: (C_/32 query tiles, B_*H_), block 256.
// Out: OHr/OHi as [b, c, h, i]  (rows of 512 = h*64+i for the GEMMs)
__global__ __launch_bounds__(256) void retention_kernel(
    const float* __restrict__ Qr, const float* __restrict__ Qi,
    const float* __restrict__ Kr, const float* __restrict__ Ki,
    const float* __restrict__ V,
    float* __restrict__ OHr, float* __restrict__ OHi,
    const float* __restrict__ gamma, const float* __restrict__ qk_scale)
{
    __shared__ float sQr[64][34], sQi[64][34];   // [i][c], pad->bank-safe col reads
    __shared__ float sKr[64][34], sKi[64][34];   // [i][d]
    __shared__ float sSr[32][32], sSi[32][32];   // [d][c]
    int tid = threadIdx.x;
    int qt = blockIdx.x, bh = blockIdx.y;
    int h = bh & 7, b = bh >> 3;
    int qc0 = qt * 32;
    size_t base = (size_t)bh * (C_ * HW_);
    for (int t = tid; t < 32 * 64; t += 256) {
        int i = t & 63, c = t >> 6;
        size_t g = base + (size_t)(qc0 + c) * HW_ + i;
        sQr[i][c] = Qr[g];
        sQi[i][c] = Qi[g];
    }
    float lg = log2f(gamma[h]);
    float inv_scale = 1.0f / qk_scale[0];
    float o_r[8] = {}, o_i[8] = {};
    int cq = tid & 31, ig = tid >> 5;       // phase-B map: (c in tile, i-block of 8)
    int cgrp = tid & 15, dgrp = tid >> 4;   // phase-A map: 2c x 2d per thread
    int c0 = cgrp * 2, d0 = dgrp * 2;
    __syncthreads();
    for (int kc0 = 0; kc0 < qc0 + 32; kc0 += 32) {
        for (int t = tid; t < 32 * 64; t += 256) {
            int i = t & 63, d = t >> 6;
            size_t g = base + (size_t)(kc0 + d) * HW_ + i;
            sKr[i][d] = Kr[g];
            sKi[i][d] = Ki[g];
        }
        __syncthreads();
        // phase A: 2x2 complex scores per thread, K-dim = 64
        float rr00 = 0, rr01 = 0, rr10 = 0, rr11 = 0;
        float im00 = 0, im01 = 0, im10 = 0, im11 = 0;
        #pragma unroll 4
        for (int i = 0; i < 64; ++i) {
            float qr0 = sQr[i][c0], qr1 = sQr[i][c0 + 1];
            float qi0 = sQi[i][c0], qi1 = sQi[i][c0 + 1];
            float kr0 = sKr[i][d0], kr1 = sKr[i][d0 + 1];
            float ki0 = sKi[i][d0], ki1 = sKi[i][d0 + 1];
            rr00 += qr0 * kr0 - qi0 * ki0;  im00 += qr0 * ki0 + qi0 * kr0;
            rr01 += qr0 * kr1 - qi0 * ki1;  im01 += qr0 * ki1 + qi0 * kr1;
            rr10 += qr1 * kr0 - qi1 * ki0;  im10 += qr1 * ki0 + qi1 * kr0;
            rr11 += qr1 * kr1 - qi1 * ki1;  im11 += qr1 * ki1 + qi1 * kr1;
        }
        {
            int qcA = qc0 + c0, qcB = qcA + 1;
            int kdA = kc0 + d0, kdB = kdA + 1;
            auto wf = [&](int delta) {
                return delta >= 0 ? exp2f(lg * (float)delta) * inv_scale : 0.0f;
            };
            float w00 = wf(qcA - kdA), w01 = wf(qcA - kdB);
            float w10 = wf(qcB - kdA), w11 = wf(qcB - kdB);
            sSr[d0][c0]         = w00 * rr00;  sSi[d0][c0]         = w00 * im00;
            sSr[d0 + 1][c0]     = w01 * rr01;  sSi[d0 + 1][c0]     = w01 * im01;
            sSr[d0][c0 + 1]     = w10 * rr10;  sSi[d0][c0 + 1]     = w10 * im10;
            sSr[d0 + 1][c0 + 1] = w11 * rr11;  sSi[d0 + 1][c0 + 1] = w11 * im11;
        }
        __syncthreads();
        // phase B: O[c, i] += S[c,d] * V[d,i]; V from global (broadcast, L1-hot)
        const float* Vg = V + base + (size_t)kc0 * HW_ + ig * 8;
        #pragma unroll 8
        for (int d = 0; d < 32; ++d) {
            float sr = sSr[d][cq], si = sSi[d][cq];
            const float4 v0 = *(const float4*)(Vg + (size_t)d * HW_);
            const float4 v1 = *(const float4*)(Vg + (size_t)d * HW_ + 4);
            o_r[0] += sr * v0.x; o_i[0] += si * v0.x;
            o_r[1] += sr * v0.y; o_i[1] += si * v0.y;
            o_r[2] += sr * v0.z; o_i[2] += si * v0.z;
            o_r[3] += sr * v0.w; o_i[3] += si * v0.w;
            o_r[4] += sr * v1.x; o_i[4] += si * v1.x;
            o_r[5] += sr * v1.y; o_i[5] += si * v1.y;
            o_r[6] += sr * v1.z; o_i[6] += si * v1.z;
            o_r[7] += sr * v1.w; o_i[7] += si * v1.w;
        }
        __syncthreads();
    }
    // per-(b,c,h) L2 norm over all 64 i (8 ig-groups x 8)
    float ss = 0;
    #pragma unroll
    for (int k = 0; k < 8; ++k) ss += o_r[k] * o_r[k] + o_i[k] * o_i[k];
    sSr[ig][cq] = ss;
    __syncthreads();
    float tot = 0;
    #pragma unroll
    for (int g2 = 0; g2 < 8; ++g2) tot += sSr[g2][cq];
    float rn = 1.0f / sqrtf(tot);
    size_t o = ((size_t)(b * C_ + qc0 + cq) * H_ + h) * HW_ + ig * 8;
    #pragma unroll
    for (int k = 0; k < 8; ++k) {
        OHr[o + k] = o_r[k] * rn;
        OHi[o + k] = o_i[k] * rn;
    }
}

// ---------------- fp32 GEMM: C[M,N] = A[M,K]*B[K,N] ----------------
// BM=BN=128, BK=8, 256 threads, 8x8 micro-tile.
// mode 0: plain store; mode 1: complex interleave (rows [0,M/2) = re, rest = im);
// mode 2: store real plane only.
// NOTE: epilogue loops MUST be fully unrolled — dynamic acc[im][in] indexing
// in a non-unrolled loop demotes the whole accumulator to scratch (R1: 52
// VGPRs, 2.2 GB scratch writes, 1950 us).
__global__ __launch_bounds__(256) void gemm_kernel(
    const float* __restrict__ A, const float* __restrict__ Bm,
    float* __restrict__ Cout, int M, int N, int K, int mode)
{
    __shared__ float sA[8][132];   // 132 floats = 528B rows, 16B-aligned
    __shared__ float sB[8][132];
    int tid = threadIdx.x;
    int bm = blockIdx.x * 128, bn = blockIdx.y * 128;
    int tx = tid & 15, ty = tid >> 4;
    int m0 = ty * 8, n0 = tx * 8;
    float acc[8][8] = {};
    for (int k0 = 0; k0 < K; k0 += 8) {
        #pragma unroll
        for (int t = tid; t < 1024; t += 256) {
            int kk = t & 7, m = t >> 3;
            sA[kk][m] = A[(size_t)(bm + m) * K + k0 + kk];
        }
        #pragma unroll
        for (int t = tid; t < 1024; t += 256) {
            int n = t & 127, kk = t >> 7;
            sB[kk][n] = Bm[(size_t)(k0 + kk) * N + bn + n];
        }
        __syncthreads();
        #pragma unroll
        for (int kk = 0; kk < 8; ++kk) {
            float a_[8], b_[8];
            *(float4*)&a_[0] = *(const float4*)&sA[kk][m0];
            *(float4*)&a_[4] = *(const float4*)&sA[kk][m0 + 4];
            *(float4*)&b_[0] = *(const float4*)&sB[kk][n0];
            *(float4*)&b_[4] = *(const float4*)&sB[kk][n0 + 4];
            #pragma unroll
            for (int im = 0; im < 8; ++im)
                #pragma unroll
                for (int in = 0; in < 8; ++in)
                    acc[im][in] += a_[im] * b_[in];
        }
        __syncthreads();
    }
    int half = M >> 1;
    #pragma unroll
    for (int im = 0; im < 8; ++im) {
        int m = bm + m0 + im;
        #pragma unroll
        for (int in = 0; in < 8; ++in) {
            int n = bn + n0 + in;
            float vv = acc[im][in];
            if (mode == 0) {
                Cout[(size_t)m * N + n] = vv;
            } else if (mode == 1) {
                if (m < half) Cout[2 * ((size_t)m * N + n)] = vv;
                else          Cout[2 * ((size_t)(m - half) * N + n) + 1] = vv;
            } else {
                if (m < half) Cout[(size_t)m * N + n] = vv;
            }
        }
    }
}

// ---------------- complex gate: oh' = oh*g / (1 + exp(-2g)), g complex ----------------
__global__ __launch_bounds__(256) void gate_kernel(
    const float* __restrict__ OHr, const float* __restrict__ OHi,
    const float* __restrict__ G,
    float* __restrict__ O2r, float* __restrict__ O2i, int n)
{
    int idx = blockIdx.x * 256 + threadIdx.x;
    if (idx >= n) return;
    float gr = G[idx], gi = G[idx + n];
    float hr = OHr[idx], hi = OHi[idx];
    float e = expf(-2.0f * gr);
    float sn, cs;
    sincosf(2.0f * gi, &sn, &cs);
    float dr = 1.0f + e * cs;     // 1 + exp(-2g) = (1 + e*cos(2gi)) - i*e*sin(2gi)
    float di = -e * sn;
    float nr = hr * gr - hi * gi; // oh * g
    float ni = hr * gi + hi * gr;
    float inv = 1.0f / (dr * dr + di * di);
    O2r[idx] = (nr * dr + ni * di) * inv;
    O2i[idx] = (ni * dr - nr * di) * inv;
}

extern "C" void kernel_launch(void* const* d_in, const int* in_sizes, int n_in,
                              void* d_out, int out_size, void* d_ws, size_t ws_size,
                              hipStream_t stream)
{
    const float* x     = (const float*)d_in[0];
    const float* WQ    = (const float*)d_in[1];
    const float* WK    = (const float*)d_in[2];
    const float* WV    = (const float*)d_in[3];
    const float* theta = (const float*)d_in[4];
    const float* gamma = (const float*)d_in[5];
    // d_in[6] target_norm: dead in reference
    const float* qk    = (const float*)d_in[7];
    const float* WO    = (const float*)d_in[8];
    const float* WG    = (const float*)d_in[9];
    float* out = (float*)d_out;
    float* w = (float*)d_ws;

    const size_t N1 = (size_t)B_ * H_ * C_ * HW_;  // 2,097,152 (also = B*C*512)
    float *Qr = w,            *Qi = w + N1,      *Kr = w + 2 * N1,
          *Ki = w + 3 * N1,   *V  = w + 4 * N1;
    float *OHr = w + 5 * N1,  *OHi = w + 6 * N1;  // contiguous -> stacked GEMM A
    float *G   = w + 7 * N1;                      // 2*N1 (re plane, im plane)
    float *O2r = w + 9 * N1,  *O2i = w + 10 * N1; // contiguous pair

    proj_kernel<<<dim3(C_ / 32, B_ * H_), 256, 0, stream>>>(
        x, WQ, WK, WV, theta, Qr, Qi, Kr, Ki, V);
    retention_kernel<<<dim3(C_ / 32, B_ * H_), 256, 0, stream>>>(
        Qr, Qi, Kr, Ki, V, OHr, OHi, gamma, qk);

    const int M = 2 * B_ * C_;  // 8192 rows: [re; im] planes
    gemm_kernel<<<dim3(M / 128, HD_ / 128), 256, 0, stream>>>(
        OHr, WG, G, M, HD_, HD_, 0);

    int n1i = (int)N1;
    gate_kernel<<<dim3((n1i + 255) / 256), 256, 0, stream>>>(
        OHr, OHi, G, O2r, O2i, n1i);

    int outmode = (out_size >= (int)(2 * N1)) ? 1 : 2;  // complex interleave vs real-only
    gemm_kernel<<<dim3(M / 128, HD_ / 128), 256, 0, stream>>>(
        O2r, WO, out, M, HD_, HD_, outmode);
}